// Round 1
// 645.849 us; speedup vs baseline: 1.0553x; 1.0553x over previous
//
#include <hip/hip_runtime.h>

// OrdinalRegressionLoss: B x 256 fp32 logits, int targets (0..255).
// row_sum = sum_{k=0..254} softplus( (k<t) ? cum_k : -cum_k ); out = mean over rows.
// Identity: softplus(z) = z/2 + |z|/2 + log1p(exp(-|z|)) =>
//   row_sum = 0.5*(2*pre - sum_c) + 0.5*sum_abs + sum_log1p,  pre = sum_{k<t} cum_k.
// One wave per row: lane i float4-loads cols 4i..4i+3 (coalesced 1KiB/row/wave).
// R4 change: persistent grid (2048 blocks) + register double-buffered 4-row batches.
// Each wave issues batch t+1's loads BEFORE computing batch t, so the vmem pipe is
// never idle during the ~900-cycle dependent scan/exp/log chain. Non-temporal loads
// (512MiB input > 256MiB L3, single-use). Partials shrink 16384 -> 2048.

#define WAVE 64
#define BLOCK 256
#define WPB (BLOCK / WAVE)
#define ROWS 4
#define NCLASS 256
#define NBLOCKS 2048

typedef float v4f __attribute__((ext_vector_type(4)));

// wave64 inclusive add-scan via DPP, 12 VALU insts, no LDS. (verified R2, absmax 0)
__device__ __forceinline__ float wave_incl_scan(float s) {
    int t;
    t = __builtin_amdgcn_update_dpp(0, __float_as_int(s), 0x111, 0xf, 0xf, true); s += __int_as_float(t); // row_shr:1
    t = __builtin_amdgcn_update_dpp(0, __float_as_int(s), 0x112, 0xf, 0xf, true); s += __int_as_float(t); // row_shr:2
    t = __builtin_amdgcn_update_dpp(0, __float_as_int(s), 0x114, 0xf, 0xf, true); s += __int_as_float(t); // row_shr:4
    t = __builtin_amdgcn_update_dpp(0, __float_as_int(s), 0x118, 0xf, 0xf, true); s += __int_as_float(t); // row_shr:8
    t = __builtin_amdgcn_update_dpp(0, __float_as_int(s), 0x142, 0xa, 0xf, true); s += __int_as_float(t); // bcast15 -> rows 1,3
    t = __builtin_amdgcn_update_dpp(0, __float_as_int(s), 0x143, 0xc, 0xf, true); s += __int_as_float(t); // bcast31 -> rows 2,3
    return s;
}

struct Buf {
    v4f v[ROWS];
    int tg[ROWS];
};

template <bool EXACT>
__device__ __forceinline__ void load_batch(Buf& bf, const v4f* __restrict__ base,
                                           const int* __restrict__ targets,
                                           long long row0, int B) {
    #pragma unroll
    for (int i = 0; i < ROWS; ++i) {
        if (EXACT || row0 + i < B) {
            bf.v[i]  = __builtin_nontemporal_load(base + (row0 + i) * (NCLASS / 4));
            bf.tg[i] = targets[row0 + i];
        }
    }
}

template <bool EXACT>
__device__ __forceinline__ void compute_batch(const Buf& bf, long long row0, int B,
                                              int k0, float lm, double& dtot) {
    const float LOG2E = 1.4426950408889634f;
    float acc_lin = 0.0f, acc_abs = 0.0f, acc_log = 0.0f;
    #pragma unroll
    for (int i = 0; i < ROWS; ++i) {
        if (!EXACT && row0 + i >= B) break;   // padded rows must not contribute
        const int t = bf.tg[i];

        const float l0 = bf.v[i].x;
        const float l1 = l0 + bf.v[i].y;
        const float l2 = l1 + bf.v[i].z;
        const float l3 = l2 + bf.v[i].w;

        const float incl = wave_incl_scan(l3);
        const float excl = incl - l3;

        const float c0 = excl + l0;
        const float c1 = excl + l1;
        const float c2 = excl + l2;
        const float c3 = excl + l3;

        const float a0 = fabsf(c0), a1 = fabsf(c1), a2 = fabsf(c2), a3 = fabsf(c3);

        // u = exp(-a); lane63's u3 masked to 0 so its log1p factor is 1
        const float u0 = __builtin_amdgcn_exp2f(-a0 * LOG2E);
        const float u1 = __builtin_amdgcn_exp2f(-a1 * LOG2E);
        const float u2 = __builtin_amdgcn_exp2f(-a2 * LOG2E);
        const float u3 = __builtin_amdgcn_exp2f(-a3 * LOG2E) * lm;

        float pr = 1.0f + u0;
        pr = __builtin_fmaf(pr, u1, pr);   // pr *= (1+u1)
        pr = __builtin_fmaf(pr, u2, pr);
        pr = __builtin_fmaf(pr, u3, pr);
        acc_log += __logf(pr);             // = sum_j log1p(u_j)

        acc_abs += a0 + a1 + a2 + a3 * lm;

        const float sum_c = c0 + c1 + c2 + c3 * lm;
        float pre = 0.0f;
        pre += (k0 + 0 < t) ? c0 : 0.0f;
        pre += (k0 + 1 < t) ? c1 : 0.0f;
        pre += (k0 + 2 < t) ? c2 : 0.0f;
        pre += (k0 + 3 < t) ? c3 : 0.0f;   // k=255 < t impossible (t<=255): auto-masked
        acc_lin += 2.0f * pre - sum_c;
    }
    dtot += 0.5 * ((double)acc_lin + (double)acc_abs) + (double)acc_log;
}

template <bool EXACT>
__global__ __launch_bounds__(BLOCK) void ordloss_main(
        const float* __restrict__ logits,
        const int*   __restrict__ targets,
        double*      __restrict__ partials,
        int B) {
    const int lane   = threadIdx.x & (WAVE - 1);
    const int wib    = threadIdx.x >> 6;
    const int waveId = blockIdx.x * WPB + wib;
    const int nWaves = gridDim.x * WPB;
    const float lm = (lane == WAVE - 1) ? 0.0f : 1.0f;  // kill k=255 contributions
    const int k0 = lane << 2;

    const v4f* base = reinterpret_cast<const v4f*>(logits) + lane;
    const long long nBatch = ((long long)B + ROWS - 1) / ROWS;

    double dtot = 0.0;

    long long bcur = waveId;
    if (bcur < nBatch) {
        Buf A, Bb;
        load_batch<EXACT>(A, base, targets, bcur * ROWS, B);
        for (;;) {
            long long bnxt = bcur + nWaves;
            if (bnxt < nBatch) {
                load_batch<EXACT>(Bb, base, targets, bnxt * ROWS, B);   // prefetch
                compute_batch<EXACT>(A, bcur * ROWS, B, k0, lm, dtot);  // overlap
                bcur = bnxt;
                bnxt = bcur + nWaves;
                if (bnxt < nBatch) {
                    load_batch<EXACT>(A, base, targets, bnxt * ROWS, B);
                    compute_batch<EXACT>(Bb, bcur * ROWS, B, k0, lm, dtot);
                    bcur = bnxt;
                } else {
                    compute_batch<EXACT>(Bb, bcur * ROWS, B, k0, lm, dtot);
                    break;
                }
            } else {
                compute_batch<EXACT>(A, bcur * ROWS, B, k0, lm, dtot);
                break;
            }
        }
    }

    // wave + block reduce (double)
    #pragma unroll
    for (int off = 32; off > 0; off >>= 1)
        dtot += __shfl_down(dtot, off, WAVE);

    __shared__ double sd[WPB];
    if (lane == 0) sd[wib] = dtot;
    __syncthreads();
    if (threadIdx.x == 0) {
        double s = 0.0;
        #pragma unroll
        for (int w = 0; w < WPB; ++w) s += sd[w];
        partials[blockIdx.x] = s;
    }
}

__global__ __launch_bounds__(512) void ordloss_reduce(
        const double* __restrict__ partials, int n,
        float* __restrict__ out, double invB) {
    __shared__ double smem[512];
    double s = 0.0;
    for (int i = threadIdx.x; i < n; i += 512) s += partials[i];
    smem[threadIdx.x] = s;
    __syncthreads();
    for (int st = 256; st > 0; st >>= 1) {
        if (threadIdx.x < st) smem[threadIdx.x] += smem[threadIdx.x + st];
        __syncthreads();
    }
    if (threadIdx.x == 0) out[0] = (float)(smem[0] * invB);
}

extern "C" void kernel_launch(void* const* d_in, const int* in_sizes, int n_in,
                              void* d_out, int out_size, void* d_ws, size_t ws_size,
                              hipStream_t stream) {
    const float* logits   = (const float*)d_in[0];
    const int*   targets  = (const int*)d_in[1];
    float*       out      = (float*)d_out;
    double*      partials = (double*)d_ws;

    const int B = in_sizes[1];
    const long long rows_per_block = (long long)WPB * ROWS;   // 16
    long long nb_needed = ((long long)B + rows_per_block - 1) / rows_per_block;
    const int NB = (int)(nb_needed < NBLOCKS ? nb_needed : NBLOCKS);

    if (B % ROWS == 0)
        ordloss_main<true><<<NB, BLOCK, 0, stream>>>(logits, targets, partials, B);
    else
        ordloss_main<false><<<NB, BLOCK, 0, stream>>>(logits, targets, partials, B);

    ordloss_reduce<<<1, 512, 0, stream>>>(partials, NB, out, 1.0 / (double)B);
}